// Round 9
// baseline (899.246 us; speedup 1.0000x reference)
//
#include <hip/hip_runtime.h>
#include <stdint.h>

#define D_MODEL 2048
#define NHEADS  16
#define HEADDIM 128
#define DFF     8192
#define BATCH   2
#define SEQ     2048
#define NTOK    (BATCH*SEQ)
#define EPS     1e-6f
#define QKV_RS  (3*D_MODEL)

typedef unsigned short u16;
typedef short  s16x8  __attribute__((ext_vector_type(8)));
typedef float  f32x4  __attribute__((ext_vector_type(4)));
typedef float  f32x16 __attribute__((ext_vector_type(16)));

__device__ __forceinline__ u16 f2bf(float f) {
  union { float f; uint32_t u; } v; v.f = f;
  uint32_t u = v.u;
  return (u16)((u + 0x7fffu + ((u >> 16) & 1u)) >> 16);
}
__device__ __forceinline__ float bf2f(u16 h) {
  union { uint32_t u; float f; } v; v.u = ((uint32_t)h) << 16;
  return v.f;
}

__device__ __forceinline__ void gload_lds16(const void* g, void* l) {
  __builtin_amdgcn_global_load_lds(
      (const __attribute__((address_space(1))) void*)g,
      (__attribute__((address_space(3))) void*)l, 16, 0, 0);
}

__device__ __forceinline__ f32x4 mfma16(s16x8 a, s16x8 b, f32x4 c) {
  return __builtin_amdgcn_mfma_f32_16x16x32_bf16(a, b, c, 0, 0, 0);
}
__device__ __forceinline__ f32x16 mfma32(s16x8 a, s16x8 b, f32x16 c) {
  return __builtin_amdgcn_mfma_f32_32x32x16_bf16(a, b, c, 0, 0, 0);
}

#define BAR()   asm volatile("s_barrier" ::: "memory")
#define LGK0()  asm volatile("s_waitcnt lgkmcnt(0)" ::: "memory")
#define VMC6()  asm volatile("s_waitcnt vmcnt(6)" ::: "memory")

// ---------------- fp32 -> bf16 conversion ----------------------------------
__device__ __forceinline__ void cvt_one(const float* in, u16* out, int i) {
  float4 v = ((const float4*)in)[i];
  uint32_t lo = (uint32_t)f2bf(v.x) | ((uint32_t)f2bf(v.y) << 16);
  uint32_t hi = (uint32_t)f2bf(v.z) | ((uint32_t)f2bf(v.w) << 16);
  uint2 st; st.x = lo; st.y = hi;
  ((uint2*)out)[i] = st;
}

__global__ __launch_bounds__(256)
void cvt_kernel(const float* __restrict__ in, u16* __restrict__ out, int n4)
{
  int idx = blockIdx.x * 256 + threadIdx.x;
  int stride = gridDim.x * 256;
  for (int i = idx; i < n4; i += stride) cvt_one(in, out, i);
}

__global__ __launch_bounds__(256)
void cvt4_kernel(const float* __restrict__ a, const float* __restrict__ b,
                 const float* __restrict__ c, const float* __restrict__ d,
                 u16* __restrict__ oa, u16* __restrict__ ob,
                 u16* __restrict__ oc, u16* __restrict__ od, int n4)
{
  int idx = blockIdx.x * 256 + threadIdx.x;
  int stride = gridDim.x * 256;
  for (int i = idx; i < 4 * n4; i += stride) {
    int w = i / n4, j = i - w * n4;
    const float* s = (w == 0) ? a : (w == 1) ? b : (w == 2) ? c : d;
    u16* o = (w == 0) ? oa : (w == 1) ? ob : (w == 2) ? oc : od;
    cvt_one(s, o, j);
  }
}

__global__ __launch_bounds__(256)
void cvt2_kernel(const float* __restrict__ a, const float* __restrict__ b,
                 u16* __restrict__ oa, u16* __restrict__ ob, int n4)
{
  int idx = blockIdx.x * 256 + threadIdx.x;
  int stride = gridDim.x * 256;
  for (int i = idx; i < 2 * n4; i += stride) {
    int w = i / n4, j = i - w * n4;
    cvt_one(w ? b : a, w ? ob : oa, j);
  }
}

// ---------------- RMSNorm: fp32 row -> bf16 row ----------------------------
__global__ __launch_bounds__(256)
void rmsnorm_kernel(const float* __restrict__ x, const float* __restrict__ w,
                    u16* __restrict__ out)
{
  int row = blockIdx.x;
  int tid = threadIdx.x;
  const float4* xr = (const float4*)(x + (size_t)row * D_MODEL);
  float4 a = xr[tid];
  float4 b = xr[tid + 256];
  float ss = a.x*a.x + a.y*a.y + a.z*a.z + a.w*a.w
           + b.x*b.x + b.y*b.y + b.z*b.z + b.w*b.w;
#pragma unroll
  for (int o = 32; o > 0; o >>= 1) ss += __shfl_xor(ss, o);
  __shared__ float red[4];
  if ((tid & 63) == 0) red[tid >> 6] = ss;
  __syncthreads();
  float tot = red[0] + red[1] + red[2] + red[3];
  float sc = rsqrtf(tot * (1.0f / D_MODEL) + EPS);
  const float4* wr = (const float4*)w;
  float4 wa = wr[tid], wb = wr[tid + 256];
  u16* orow = out + (size_t)row * D_MODEL;
  uint2 s0, s1;
  s0.x = (uint32_t)f2bf(a.x*wa.x*sc) | ((uint32_t)f2bf(a.y*wa.y*sc) << 16);
  s0.y = (uint32_t)f2bf(a.z*wa.z*sc) | ((uint32_t)f2bf(a.w*wa.w*sc) << 16);
  s1.x = (uint32_t)f2bf(b.x*wb.x*sc) | ((uint32_t)f2bf(b.y*wb.y*sc) << 16);
  s1.y = (uint32_t)f2bf(b.z*wb.z*sc) | ((uint32_t)f2bf(b.w*wb.w*sc) << 16);
  ((uint2*)orow)[tid] = s0;
  ((uint2*)orow)[tid + 256] = s1;
}

// ---------------- GEMM 128x128 (m97 structure + swizzle) -------------------
// 2 blocks/CU. Used for wo-proj (K=2048) and down-proj (K=8192), grid 512.
#define BM 128
#define BN 128
#define BK 64

template<int EPI>
__global__ __launch_bounds__(256, 2)
void gemm_bt(const u16* __restrict__ A, const u16* __restrict__ B,
             void* __restrict__ Cout, const float* __restrict__ aux,
             int M, int N, int K)
{
  __shared__ u16 As[BM * BK];
  __shared__ u16 Bs[BN * BK];
  const int nbn = N / BN;
  int bid = blockIdx.x;
  int swz = (gridDim.x & 7) ? bid : ((bid & 7) * (gridDim.x >> 3) + (bid >> 3));
  const int bm = swz / nbn, bn = swz % nbn;
  const int m0 = bm * BM, n0 = bn * BN;
  const int tid = threadIdx.x;
  const int lane = tid & 63;
  const int wm = tid >> 7, wn = (tid >> 6) & 1;
  const int lr = lane & 15, lg = lane >> 4;

  f32x4 acc[4][4] = {};

  for (int k0 = 0; k0 < K; k0 += BK) {
#pragma unroll
    for (int i = 0; i < 4; ++i) {
      int c = i * 256 + tid;
      int row = c >> 3, cr = c & 7;
      int g = cr ^ (row & 7);
      gload_lds16(A + (size_t)(m0 + row) * K + k0 + (g << 3), &As[c * 8]);
      gload_lds16(B + (size_t)(n0 + row) * K + k0 + (g << 3), &Bs[c * 8]);
    }
    __syncthreads();
#pragma unroll
    for (int kk = 0; kk < BK; kk += 32) {
      s16x8 a[4], b[4];
#pragma unroll
      for (int m = 0; m < 4; ++m) {
        int row = wm * 64 + m * 16 + lr;
        int j = (kk >> 3) + lg;
        a[m] = *(const s16x8*)&As[row * BK + ((j ^ (row & 7)) << 3)];
      }
#pragma unroll
      for (int n = 0; n < 4; ++n) {
        int row = wn * 64 + n * 16 + lr;
        int j = (kk >> 3) + lg;
        b[n] = *(const s16x8*)&Bs[row * BK + ((j ^ (row & 7)) << 3)];
      }
#pragma unroll
      for (int m = 0; m < 4; ++m)
#pragma unroll
        for (int n = 0; n < 4; ++n)
          acc[m][n] = mfma16(a[m], b[n], acc[m][n]);
    }
    __syncthreads();
  }

#pragma unroll
  for (int m = 0; m < 4; ++m) {
#pragma unroll
    for (int n = 0; n < 4; ++n) {
      int col = n0 + wn * 64 + n * 16 + lr;
#pragma unroll
      for (int r = 0; r < 4; ++r) {
        int row = m0 + wm * 64 + m * 16 + lg * 4 + r;
        size_t idx = (size_t)row * N + col;
        float v = acc[m][n][r];
        if (EPI == 0) {
          ((u16*)Cout)[idx] = f2bf(v);
        } else if (EPI == 1) {
          float up = bf2f(((u16*)Cout)[idx]);
          float s = v / (1.0f + __expf(-v));
          ((u16*)Cout)[idx] = f2bf(s * up);
        } else if (EPI == 2) {
          ((float*)Cout)[idx] = aux[idx] + v;
        } else {
          ((float*)Cout)[idx] += v;
        }
      }
    }
  }
}

// ---------------- GEMM 256x256: 8-phase derived-waits, 32x32x16 MFMA -------
// r11 schedule (regions: bit6(row) for A, bit5(row) for B; permutation folded
// into global source addr; vmcnt(6) at ph4/ph8; linear bid).
// r15: MFMA shape 16x16x32 -> 32x32x16. Same FLOP, same LDS reads (16A+8B
// ds_read_b128 per K-tile per wave, same addresses), but matrix-pipe time
// per phase 620->516 cyc (m119: 2495 vs 2075 TF rate) and HALF the MFMA
// instructions in the setprio window. acc = 8 x f32x16 (128 VGPR, same).
// C/D layout (HW-verified m74/m101): col=lane&31, row=(reg&3)+8(reg>>2)+4(lane>>5).
// A/B frag: row=lane&31, k-octet=lane>>5 (symmetry with 16x16 working code).
template<int EPI>
__global__ __launch_bounds__(512, 2)
void gemm256(const u16* __restrict__ A, const u16* __restrict__ B,
             void* __restrict__ Cout, const float* __restrict__ aux,
             int M, int N, int K)
{
  __shared__ u16 As[2][2 * 8192];
  __shared__ u16 Bs[2][2 * 8192];
  const int nbn = N >> 8;
  const int bm = blockIdx.x / nbn, bn = blockIdx.x % nbn;
  const int m0 = bm << 8, n0 = bn << 8;
  const int tid = threadIdx.x, lane = tid & 63;
  const int wid = tid >> 6;
  const int wm = wid >> 2, wn = wid & 3;      // 2 x 4 wave grid, 128x64/wave
  const int l31 = lane & 31, lo8 = lane >> 5;

  f32x16 acc[4][2] = {};
  s16x8 aE[8], aO[8], bE[4], bO[4];

  // stage A region rh of tile ts into buf: rows (r>>6)*128 + rh*64 + (r&63)
  auto stA = [&](int buf, int rh, int ts) {
    const u16* src = A + (size_t)m0 * K + ts * 64;
    u16* dst = &As[buf][rh * 8192];
#pragma unroll
    for (int i = 0; i < 2; ++i) {
      int c = i * 512 + tid;
      int r = c >> 3, cr = c & 7;
      int grow = ((r >> 6) << 7) | (rh << 6) | (r & 63);
      int g = cr ^ (r & 7);
      gload_lds16(src + (size_t)grow * K + (g << 3), dst + c * 8);
    }
  };
  // stage B region rh: rows (r>>5)*64 + rh*32 + (r&31)
  auto stB = [&](int buf, int rh, int ts) {
    const u16* src = B + (size_t)n0 * K + ts * 64;
    u16* dst = &Bs[buf][rh * 8192];
#pragma unroll
    for (int i = 0; i < 2; ++i) {
      int c = i * 512 + tid;
      int r = c >> 3, cr = c & 7;
      int grow = ((r >> 5) << 6) | (rh << 5) | (r & 31);
      int g = cr ^ (r & 7);
      gload_lds16(src + (size_t)grow * K + (g << 3), dst + c * 8);
    }
  };
  // read A region mh: 2 mtiles x 4 ksteps = 8 x ds_read_b128
  // subrow = wm*64 + t2*32 + l31 (region holds bit6 of global row)
  auto rdA = [&](int buf, int mh, s16x8* d) {
#pragma unroll
    for (int t2 = 0; t2 < 2; ++t2)
#pragma unroll
      for (int ks = 0; ks < 4; ++ks) {
        int sr = wm * 64 + t2 * 32 + l31;
        int jj = (ks * 2 + lo8) ^ (sr & 7);
        d[t2 * 4 + ks] = *(const s16x8*)&As[buf][mh * 8192 + sr * 64 + (jj << 3)];
      }
  };
  // read B region nh: 1 ntile x 4 ksteps = 4 x ds_read_b128
  // subrow = wn*32 + l31 (region holds bit5 of global row)
  auto rdB = [&](int buf, int nh, s16x8* d) {
#pragma unroll
    for (int ks = 0; ks < 4; ++ks) {
      int sr = wn * 32 + l31;
      int jj = (ks * 2 + lo8) ^ (sr & 7);
      d[ks] = *(const s16x8*)&Bs[buf][nh * 8192 + sr * 64 + (jj << 3)];
    }
  };
  // one C-quadrant x K=64 = 8 MFMA of 32x32x16
  auto MF = [&](int mh, int nh, const s16x8* a, const s16x8* b) {
    __builtin_amdgcn_s_setprio(1);
#pragma unroll
    for (int t2 = 0; t2 < 2; ++t2)
#pragma unroll
      for (int ks = 0; ks < 4; ++ks)
        acc[mh * 2 + t2][nh] = mfma32(a[t2 * 4 + ks], b[ks], acc[mh * 2 + t2][nh]);
    __builtin_amdgcn_s_setprio(0);
  };

  const int nt = K >> 6;

  // prologue: tile0 (buf0) then tile1 (buf1, A0 first). 16 vm-ops issued;
  // VMC6 drains oldest 10 = all of t0 + A0(t1); {B0,B1,A1}(t1) stay flying.
  stA(0, 0, 0); stB(0, 0, 0); stB(0, 1, 0); stA(0, 1, 0);
  stA(1, 0, 1); stB(1, 0, 1); stB(1, 1, 1); stA(1, 1, 1);
  VMC6();
  BAR();
  rdA(0, 0, aE);      // A0(0) pre-read
  LGK0();
  BAR();              // all waves' A0(0) reads done before ph1 stage

#pragma unroll 1
  for (int it = 0; it < (nt >> 1); ++it) {
    const int u = it << 1;
    const int s2 = (u + 2 < nt) ? u + 2 : nt - 1;
    const int s3 = (u + 3 < nt) ? u + 3 : nt - 1;

    // ph1
    rdB(0, 0, bE); stA(0, 0, s2); BAR(); LGK0();
    MF(0, 0, aE, bE); BAR();
    // ph2
    rdB(0, 1, bO); stB(0, 0, s2); BAR(); LGK0();
    MF(0, 1, aE, bO); BAR();
    // ph3
    rdA(0, 1, aO); stB(0, 1, s2); BAR(); LGK0();
    MF(1, 1, aO, bO); BAR();
    // ph4
    rdA(1, 0, aE); stA(0, 1, s2); BAR(); LGK0();
    MF(1, 0, aO, bE); VMC6(); BAR();
    // ph5
    rdB(1, 0, bE); stA(1, 0, s3); BAR(); LGK0();
    MF(0, 0, aE, bE); BAR();
    // ph6
    rdB(1, 1, bO); stB(1, 0, s3); BAR(); LGK0();
    MF(0, 1, aE, bO); BAR();
    // ph7
    rdA(1, 1, aO); stB(1, 1, s3); BAR(); LGK0();
    MF(1, 1, aO, bO); BAR();
    // ph8
    rdA(0, 0, aE); stA(1, 1, s3); BAR(); LGK0();
    MF(1, 0, aO, bE); VMC6(); BAR();
  }

  asm volatile("s_waitcnt vmcnt(0)" ::: "memory");

  // ---- epilogue: C/D layout col=lane&31, row=(reg&3)+8(reg>>2)+4(lane>>5)
#pragma unroll
  for (int mt = 0; mt < 4; ++mt) {
#pragma unroll
    for (int ntt = 0; ntt < 2; ++ntt) {
      int col = n0 + wn * 64 + ntt * 32 + l31;
#pragma unroll
      for (int reg = 0; reg < 16; ++reg) {
        int row = m0 + wm * 128 + mt * 32 + (reg & 3) + 8 * (reg >> 2) + 4 * lo8;
        size_t idx = (size_t)row * N + col;
        float v = acc[mt][ntt][reg];
        if (EPI == 0) {
          ((u16*)Cout)[idx] = f2bf(v);
        } else if (EPI == 1) {
          float up = bf2f(((u16*)Cout)[idx]);
          float s = v / (1.0f + __expf(-v));
          ((u16*)Cout)[idx] = f2bf(s * up);
        } else if (EPI == 2) {
          ((float*)Cout)[idx] = aux[idx] + v;
        } else {
          ((float*)Cout)[idx] += v;
        }
      }
    }
  }
}

// ---------------- Flash attention (causal, in-block balanced) --------------
// r9: block p owns q-tiles lo=p and hi=31-p; every block does 33 work units.
// r12: T13 defer-max (THR=8). r14: single-Vt + two barriers (dbuf regressed);
// XCD-group swizzle (16 blocks sharing one (b,h)'s KV land on one XCD -> KV
// L2-resident; FETCH 269MB -> collapsed).
#define QBLK 128
#define KVBLK 64

__global__ __launch_bounds__(256, 2)
void attn_kernel(const u16* __restrict__ QKV, u16* __restrict__ O)
{
  __shared__ u16 Ks[2][KVBLK * HEADDIM];   // 32KB dbuf, chunk ^= row&7
  __shared__ u16 Vt[HEADDIM * KVBLK];      // 16KB single, transposed
  __shared__ u16 Pw[4][32 * KVBLK];        // 16KB per-wave P

  const int bid = blockIdx.x;
  const int swz = ((bid & 7) << 6) | (bid >> 3);   // XCD-group swizzle
  const int p  = swz & 15;                 // pair index
  const int h  = (swz >> 4) & (NHEADS - 1);
  const int b  = swz >> 8;
  const int tid = threadIdx.x, lane = tid & 63, wid = tid >> 6;
  const int lr = lane & 15, lg = lane >> 4;
  const size_t tokbase = (size_t)b * SEQ;
  const int hoff = h * HEADDIM;
  const int qrow0 = p * 64 + wid * 16;         // m=0 rows (lo tile)
  const int qrow1 = (31 - p) * 64 + wid * 16;  // m=1 rows (hi tile)
  const int nkb = 32 - p;
  const float scale = 0.08838834764831845f;

  s16x8 qf[2][4];
#pragma unroll
  for (int c = 0; c < 4; ++c) {
    qf[0][c] = *(const s16x8*)(QKV + (tokbase + qrow0 + lr) * QKV_RS
                               + hoff + c * 32 + lg * 8);
    qf[1][c] = *(const s16x8*)(QKV + (tokbase + qrow1 + lr) * QKV_RS
                               + hoff + c * 32 + lg * 8);
  }

  f32x4 o_acc[2][8] = {};
  float m_run[2][4], l_run[2][4];
#pragma unroll
  for (int m = 0; m < 2; ++m)
#pragma unroll
    for (int r = 0; r < 4; ++r) { m_run[m][r] = -1e30f; l_run[m][r] = 0.0f; }

  s16x8 v0[2], v1[2];

  // prologue: K tile 0 -> Ks[0], V tile 0 -> Vt
  {
    const u16* kbase = QKV + tokbase * QKV_RS + D_MODEL + hoff;
#pragma unroll
    for (int it = 0; it < 4; ++it) {
      int c = it * 256 + tid;
      int row = c >> 4, cr = c & 15;
      int g = cr ^ (row & 7);
      gload_lds16(kbase + (size_t)row * QKV_RS + g * 8, &Ks[0][c * 8]);
    }
    const u16* vbase = QKV + tokbase * QKV_RS + 2 * D_MODEL + hoff;
#pragma unroll
    for (int i = 0; i < 2; ++i) {
      int pi = i * 256 + tid;
      int rp = pi >> 4, dc = pi & 15;
      const u16* vp = vbase + (size_t)(rp * 2) * QKV_RS + dc * 8;
      v0[i] = *(const s16x8*)vp;
      v1[i] = *(const s16x8*)(vp + QKV_RS);
    }
    uint32_t* vt = (uint32_t*)&Vt[0];
#pragma unroll
    for (int i = 0; i < 2; ++i) {
      int pi = i * 256 + tid;
      int rp = pi >> 4, dc = pi & 15;
      int k0 = rp * 2;
      int base = ((k0 >> 3) ^ (dc & 7)) * 4 + ((k0 >> 1) & 3);
#pragma unroll
      for (int j = 0; j < 8; ++j)
        vt[(dc * 8 + j) * (KVBLK / 2) + base] =
            (uint32_t)(u16)v0[i][j] | ((uint32_t)(u16)v1[i][j] << 16);
    }
  }
  __syncthreads();

  for (int kb = 0; kb < nkb; ++kb) {
    const int buf = kb & 1;
    const bool nb = (kb + 1 < nkb);
    const bool act0 = (kb <= p);

    if (nb) {
      const u16* kbase = QKV + (tokbase + (size_t)(kb + 1) * KVBLK) * QKV_RS + D_MODEL + hoff;
#pragma unroll
      for (int it = 0; it < 4; ++it) {
        int c = it * 256 + tid;
        int row = c >> 4, cr = c & 15;
        int g = cr ^ (row & 7);
        gload_lds16(kbase + (size_t)row * QKV_RS + g * 8, &Ks[buf ^ 1][c * 8]);
      }
      const u16* vbase = QKV + (tokbase + (size_t)(kb + 1) * KVBLK) * QKV_RS + 2 * D_MODEL + hoff;
#pragma unroll
      for (int i = 0; i < 2; ++i) {
        int pi = i * 256 + tid;
        int rp = pi >> 4, dc = pi & 15;
        const u16* vp = vbase + (size_t)(rp * 2) * QKV_RS + dc * 8;
        v0[i] = *(const s16x8*)vp;
        v1[i] = *(const s16x8*)(vp + QKV_RS);
      }
    }

    // ---- QK^T ----
    f32x4 s_acc[2][4] = {};
#pragma unroll
    for (int kk = 0; kk < 4; ++kk) {
      s16x8 kf[4];
#pragma unroll
      for (int n = 0; n < 4; ++n) {
        int row = n * 16 + lr;
        int ch = (kk * 4 + lg) ^ (row & 7);
        kf[n] = *(const s16x8*)&Ks[buf][row * HEADDIM + ch * 8];
      }
#pragma unroll
      for (int m = 0; m < 2; ++m) {
        if (m == 0 && !act0) continue;
#pragma unroll
        for (int n = 0; n < 4; ++n)
          s_acc[m][n] = mfma16(qf[m][kk], kf[n], s_acc[m][n]);
      }
    }

    // ---- online softmax (defer-max, THR=8) ----
#pragma unroll
    for (int m = 0; m < 2; ++m) {
      if (m == 0 && !act0) continue;
      const int qb_ = (m == 0) ? qrow0 : qrow1;
      float tmax[4] = {-1e30f, -1e30f, -1e30f, -1e30f};
      float sv[4][4];
#pragma unroll
      for (int n = 0; n < 4; ++n) {
        int key = kb * KVBLK + n * 16 + lr;
#pragma unroll
        for (int r = 0; r < 4; ++r) {
          int q = qb_ + lg * 4 + r;
          float s = s_acc[m][n][r] * scale;
          if (key > q) s = -1e30f;
          sv[n][r] = s;
          tmax[r] = fmaxf(tmax[r], s);
        }
      }
#pragma unroll
      for (int o = 1; o < 16; o <<= 1)
#pragma unroll
        for (int r = 0; r < 4; ++r)
          tmax[r] = fmaxf(tmax[r], __shfl_xor(tmax[r], o));

      int small = (tmax[0] <= m_run[m][0] + 8.0f) &&
                  (tmax[1] <= m_run[m][1] + 8.0f) &&
                  (tmax[2] <= m_run[m][2] + 8.0f) &&
                  (tmax[3] <= m_run[m][3] + 8.0f);
      if (!__all(small)) {
        float pf[4];
#pragma unroll
        for (int r = 0; r < 4; ++r) {
          float mn = fmaxf(m_run[m][r], tmax[r]);
          pf[r] = __expf(m_run[m][r] - mn);
          m_run[m][r] = mn;
        }
#pragma unroll
        for (int r = 0; r < 4; ++r) l_run[m][r] *= pf[r];
#pragma unroll
        for (int t = 0; t < 8; ++t)
#pragma unroll
          for (int r = 0; r < 4; ++r)
            o_acc[m][t][r] *= pf[r];
      }

      float psum[4] = {0.0f, 0.0f, 0.0f, 0.0f};
#pragma unroll
      for (int n = 0; n < 4; ++n) {
        int keyl = n * 16 + lr;
#pragma unroll
        for (int r = 0; r < 4; ++r) {
          float pv = __expf(sv[n][r] - m_run[m][r]);
          psum[r] += pv;
          int ql = m * 16 + lg * 4 + r;
          int ch = (keyl >> 3) ^ (ql & 7);
          Pw[wid][ql * KVBLK + ch * 8 + (keyl & 7)] = f2bf(pv);
        }
      }
#pragma unroll
      for (int o = 1; o < 16; o <<= 1)
#pragma unroll
        for (int r = 0; r < 4; ++r)
          psum[r] += __shfl_xor(psum[r], o);
#pragma unroll
      for (int r = 0; r < 4; ++r)
        l_run[m][r] += psum[r];
    }

    // ---- PV ----
#pragma unroll
    for (int kk = 0; kk < 2; ++kk) {
      s16x8 pa[2];
#pragma unroll
      for (int m = 0; m < 2; ++m) {
        int ql = m * 16 + lr;
        int ch = (kk * 4 + lg) ^ (ql & 7);
        pa[m] = *(const s16x8*)&Pw[wid][ql * KVBLK + ch * 8];
      }
#pragma unroll
      for (int t = 0; t < 8; ++t) {
        int d = t * 16 + lr;
        int ch = (kk * 4 + lg) ^ ((d >> 3) & 7);
        s16x8 vf = *(const s16x8*)&Vt[d * KVBLK + ch * 8];
#pragma unroll
        for (int m = 0; m < 2; ++m) {
          if (m == 0 && !act0) continue;
          o_acc[m][t] = mfma16(pa[m], vf, o_acc[m][t]);
        }
      }
    }

    // single V buffer: wait for all waves' PV reads, then overwrite
    __syncthreads();
    if (nb) {
      uint32_t* vt = (uint32_t*)&Vt[0];
#pragma unroll
      for (int i = 0; i < 2; ++i) {
        int pi = i * 256 + tid;
        int rp = pi >> 4, dc = pi & 15;
        int k0 = rp * 2;
        int base = ((k0 >> 3) ^ (dc & 7)) * 4 + ((k0 >> 1) & 3);
#pragma unroll
        for (int j = 0; j < 8; ++j)
          vt[(dc * 8 + j) * (KVBLK / 2) + base] =
              (uint32_t)(u16)v0[i][j] | ((uint32_t)(u16)v1[i][j] << 16);
      }
    }
    __syncthreads();
  }

#pragma unroll
  for (int m = 0; m < 2; ++m)
#pragma unroll
    for (int t = 0; t < 8; ++t)
#pragma unroll
      for (int r = 0; r < 4; ++r) {
        int q = ((m == 0) ? qrow0 : qrow1) + lg * 4 + r;
        O[(tokbase + q) * D_MODEL + hoff + t * 16 + lr] =
            f2bf(o_acc[m][t][r] / l_run[m][r]);
      }
}

// ---------------------------------------------------------------------------
extern "C" void kernel_launch(void* const* d_in, const int* in_sizes, int n_in,
                              void* d_out, int out_size, void* d_ws, size_t ws_size,
                              hipStream_t stream)
{
  const float* hidden = (const float*)d_in[0];
  const float* wq    = (const float*)d_in[1];
  const float* wk    = (const float*)d_in[2];
  const float* wv    = (const float*)d_in[3];
  const float* wo    = (const float*)d_in[4];
  const float* wgate = (const float*)d_in[5];
  const float* wup   = (const float*)d_in[6];
  const float* wdown = (const float*)d_in[7];
  const float* ln1   = (const float*)d_in[8];
  const float* ln2   = (const float*)d_in[9];
  float* out = (float*)d_out;

  const size_t TD = (size_t)NTOK * D_MODEL;
  const size_t DD = (size_t)D_MODEL * D_MODEL;
  const size_t FD = (size_t)DFF * D_MODEL;

  u16* XN  = (u16*)d_ws;       // [NTOK, D]
  u16* QKV = XN + TD;          // [NTOK, 3D]  (later: w_up, then w_down)
  u16* AO  = QKV + 3 * TD;     // [NTOK, D]
  u16* WB  = AO + TD;          // wq|wk|wv|wo  (later: w_gate)
  u16* GU  = WB + FD;          // [NTOK, DFF]

  dim3 b256(256), b512(512);

  // all 4 attention weights in one launch
  cvt4_kernel<<<dim3(2048), b256, 0, stream>>>(
      wq, wk, wv, wo, WB + 0 * DD, WB + 1 * DD, WB + 2 * DD, WB + 3 * DD,
      (int)(DD / 4));

  rmsnorm_kernel<<<dim3(NTOK), b256, 0, stream>>>(hidden, ln1, XN);

  // fused QKV projection: [4096,2048] x [6144,2048]^T
  gemm256<0><<<dim3(16 * 24), b512, 0, stream>>>(XN, WB, QKV, nullptr, NTOK, 3 * D_MODEL, D_MODEL);

  attn_kernel<<<dim3(BATCH * NHEADS * (SEQ / QBLK)), b256, 0, stream>>>(QKV, AO);

  // out = hidden + AO @ wo^T   (N=2048 -> 128^2 kernel, 512 blocks)
  gemm_bt<2><<<dim3(32 * 16), b256, 0, stream>>>(AO, WB + 3 * DD, out, hidden, NTOK, D_MODEL, D_MODEL);

  // MLP weight conversions (gate+up batched)
  cvt2_kernel<<<dim3(4096), b256, 0, stream>>>(wgate, wup, WB, QKV, (int)(FD / 4));

  rmsnorm_kernel<<<dim3(NTOK), b256, 0, stream>>>(out, ln2, XN);

  gemm256<0><<<dim3(16 * 32), b512, 0, stream>>>(XN, QKV, GU, nullptr, NTOK, DFF, D_MODEL);
  gemm256<1><<<dim3(16 * 32), b512, 0, stream>>>(XN, WB, GU, nullptr, NTOK, DFF, D_MODEL);

  cvt_kernel<<<dim3(8192), b256, 0, stream>>>(wdown, QKV, (int)(FD / 4));

  // out += GU @ w_down^T   (N=2048 -> 128^2 kernel)
  gemm_bt<3><<<dim3(32 * 16), b256, 0, stream>>>(GU, QKV, out, nullptr, NTOK, D_MODEL, DFF);
}

// Round 10
// 839.904 us; speedup vs baseline: 1.0707x; 1.0707x over previous
//
#include <hip/hip_runtime.h>
#include <stdint.h>

#define D_MODEL 2048
#define NHEADS  16
#define HEADDIM 128
#define DFF     8192
#define BATCH   2
#define SEQ     2048
#define NTOK    (BATCH*SEQ)
#define EPS     1e-6f
#define QKV_RS  (3*D_MODEL)

typedef unsigned short u16;
typedef short  s16x8 __attribute__((ext_vector_type(8)));
typedef float  f32x4 __attribute__((ext_vector_type(4)));

__device__ __forceinline__ u16 f2bf(float f) {
  union { float f; uint32_t u; } v; v.f = f;
  uint32_t u = v.u;
  return (u16)((u + 0x7fffu + ((u >> 16) & 1u)) >> 16);
}
__device__ __forceinline__ float bf2f(u16 h) {
  union { uint32_t u; float f; } v; v.u = ((uint32_t)h) << 16;
  return v.f;
}

__device__ __forceinline__ void gload_lds16(const void* g, void* l) {
  __builtin_amdgcn_global_load_lds(
      (const __attribute__((address_space(1))) void*)g,
      (__attribute__((address_space(3))) void*)l, 16, 0, 0);
}

__device__ __forceinline__ f32x4 mfma16(s16x8 a, s16x8 b, f32x4 c) {
  return __builtin_amdgcn_mfma_f32_16x16x32_bf16(a, b, c, 0, 0, 0);
}

#define BAR()   asm volatile("s_barrier" ::: "memory")
#define LGK0()  asm volatile("s_waitcnt lgkmcnt(0)" ::: "memory")
#define VMC6()  asm volatile("s_waitcnt vmcnt(6)" ::: "memory")

// ---------------- fp32 -> bf16 conversion ----------------------------------
__device__ __forceinline__ void cvt_one(const float* in, u16* out, int i) {
  float4 v = ((const float4*)in)[i];
  uint32_t lo = (uint32_t)f2bf(v.x) | ((uint32_t)f2bf(v.y) << 16);
  uint32_t hi = (uint32_t)f2bf(v.z) | ((uint32_t)f2bf(v.w) << 16);
  uint2 st; st.x = lo; st.y = hi;
  ((uint2*)out)[i] = st;
}

__global__ __launch_bounds__(256)
void cvt_kernel(const float* __restrict__ in, u16* __restrict__ out, int n4)
{
  int idx = blockIdx.x * 256 + threadIdx.x;
  int stride = gridDim.x * 256;
  for (int i = idx; i < n4; i += stride) cvt_one(in, out, i);
}

__global__ __launch_bounds__(256)
void cvt4_kernel(const float* __restrict__ a, const float* __restrict__ b,
                 const float* __restrict__ c, const float* __restrict__ d,
                 u16* __restrict__ oa, u16* __restrict__ ob,
                 u16* __restrict__ oc, u16* __restrict__ od, int n4)
{
  int idx = blockIdx.x * 256 + threadIdx.x;
  int stride = gridDim.x * 256;
  for (int i = idx; i < 4 * n4; i += stride) {
    int w = i / n4, j = i - w * n4;
    const float* s = (w == 0) ? a : (w == 1) ? b : (w == 2) ? c : d;
    u16* o = (w == 0) ? oa : (w == 1) ? ob : (w == 2) ? oc : od;
    cvt_one(s, o, j);
  }
}

__global__ __launch_bounds__(256)
void cvt2_kernel(const float* __restrict__ a, const float* __restrict__ b,
                 u16* __restrict__ oa, u16* __restrict__ ob, int n4)
{
  int idx = blockIdx.x * 256 + threadIdx.x;
  int stride = gridDim.x * 256;
  for (int i = idx; i < 2 * n4; i += stride) {
    int w = i / n4, j = i - w * n4;
    cvt_one(w ? b : a, w ? ob : oa, j);
  }
}

// ---------------- RMSNorm: fp32 row -> bf16 row ----------------------------
__global__ __launch_bounds__(256)
void rmsnorm_kernel(const float* __restrict__ x, const float* __restrict__ w,
                    u16* __restrict__ out)
{
  int row = blockIdx.x;
  int tid = threadIdx.x;
  const float4* xr = (const float4*)(x + (size_t)row * D_MODEL);
  float4 a = xr[tid];
  float4 b = xr[tid + 256];
  float ss = a.x*a.x + a.y*a.y + a.z*a.z + a.w*a.w
           + b.x*b.x + b.y*b.y + b.z*b.z + b.w*b.w;
#pragma unroll
  for (int o = 32; o > 0; o >>= 1) ss += __shfl_xor(ss, o);
  __shared__ float red[4];
  if ((tid & 63) == 0) red[tid >> 6] = ss;
  __syncthreads();
  float tot = red[0] + red[1] + red[2] + red[3];
  float sc = rsqrtf(tot * (1.0f / D_MODEL) + EPS);
  const float4* wr = (const float4*)w;
  float4 wa = wr[tid], wb = wr[tid + 256];
  u16* orow = out + (size_t)row * D_MODEL;
  uint2 s0, s1;
  s0.x = (uint32_t)f2bf(a.x*wa.x*sc) | ((uint32_t)f2bf(a.y*wa.y*sc) << 16);
  s0.y = (uint32_t)f2bf(a.z*wa.z*sc) | ((uint32_t)f2bf(a.w*wa.w*sc) << 16);
  s1.x = (uint32_t)f2bf(b.x*wb.x*sc) | ((uint32_t)f2bf(b.y*wb.y*sc) << 16);
  s1.y = (uint32_t)f2bf(b.z*wb.z*sc) | ((uint32_t)f2bf(b.w*wb.w*sc) << 16);
  ((uint2*)orow)[tid] = s0;
  ((uint2*)orow)[tid + 256] = s1;
}

// ---------------- GEMM 128x128 (m97 structure + swizzle) -------------------
// 2 blocks/CU. Used for wo-proj (K=2048) and down-proj (K=8192), grid 512.
#define BM 128
#define BN 128
#define BK 64

template<int EPI>
__global__ __launch_bounds__(256, 2)
void gemm_bt(const u16* __restrict__ A, const u16* __restrict__ B,
             void* __restrict__ Cout, const float* __restrict__ aux,
             int M, int N, int K)
{
  __shared__ u16 As[BM * BK];
  __shared__ u16 Bs[BN * BK];
  const int nbn = N / BN;
  int bid = blockIdx.x;
  int swz = (gridDim.x & 7) ? bid : ((bid & 7) * (gridDim.x >> 3) + (bid >> 3));
  const int bm = swz / nbn, bn = swz % nbn;
  const int m0 = bm * BM, n0 = bn * BN;
  const int tid = threadIdx.x;
  const int lane = tid & 63;
  const int wm = tid >> 7, wn = (tid >> 6) & 1;
  const int lr = lane & 15, lg = lane >> 4;

  f32x4 acc[4][4] = {};

  for (int k0 = 0; k0 < K; k0 += BK) {
#pragma unroll
    for (int i = 0; i < 4; ++i) {
      int c = i * 256 + tid;
      int row = c >> 3, cr = c & 7;
      int g = cr ^ (row & 7);
      gload_lds16(A + (size_t)(m0 + row) * K + k0 + (g << 3), &As[c * 8]);
      gload_lds16(B + (size_t)(n0 + row) * K + k0 + (g << 3), &Bs[c * 8]);
    }
    __syncthreads();
#pragma unroll
    for (int kk = 0; kk < BK; kk += 32) {
      s16x8 a[4], b[4];
#pragma unroll
      for (int m = 0; m < 4; ++m) {
        int row = wm * 64 + m * 16 + lr;
        int j = (kk >> 3) + lg;
        a[m] = *(const s16x8*)&As[row * BK + ((j ^ (row & 7)) << 3)];
      }
#pragma unroll
      for (int n = 0; n < 4; ++n) {
        int row = wn * 64 + n * 16 + lr;
        int j = (kk >> 3) + lg;
        b[n] = *(const s16x8*)&Bs[row * BK + ((j ^ (row & 7)) << 3)];
      }
#pragma unroll
      for (int m = 0; m < 4; ++m)
#pragma unroll
        for (int n = 0; n < 4; ++n)
          acc[m][n] = mfma16(a[m], b[n], acc[m][n]);
    }
    __syncthreads();
  }

#pragma unroll
  for (int m = 0; m < 4; ++m) {
#pragma unroll
    for (int n = 0; n < 4; ++n) {
      int col = n0 + wn * 64 + n * 16 + lr;
#pragma unroll
      for (int r = 0; r < 4; ++r) {
        int row = m0 + wm * 64 + m * 16 + lg * 4 + r;
        size_t idx = (size_t)row * N + col;
        float v = acc[m][n][r];
        if (EPI == 0) {
          ((u16*)Cout)[idx] = f2bf(v);
        } else if (EPI == 1) {
          float up = bf2f(((u16*)Cout)[idx]);
          float s = v / (1.0f + __expf(-v));
          ((u16*)Cout)[idx] = f2bf(s * up);
        } else if (EPI == 2) {
          ((float*)Cout)[idx] = aux[idx] + v;
        } else {
          ((float*)Cout)[idx] += v;
        }
      }
    }
  }
}

// ---------------- GEMM 256x256: derived-waits 8-phase, PERMUTED regions ----
// r11 schedule (verified, 202us/28% MfmaUtil, 0 bank conflicts). Linear bid
// (r12's T1 swizzle destroyed B-reuse: FETCH 131->303MB). 16x16x32 MFMA
// (r15's 32x32x16 swap introduced 12.7M bank conflicts, +15us/dispatch —
// the 32-row/2-octet-group read geometry conflicts where 16-row/4-group
// does not; reverted).
template<int EPI>
__global__ __launch_bounds__(512, 2)
void gemm256(const u16* __restrict__ A, const u16* __restrict__ B,
             void* __restrict__ Cout, const float* __restrict__ aux,
             int M, int N, int K)
{
  __shared__ u16 As[2][2 * 8192];
  __shared__ u16 Bs[2][2 * 8192];
  const int nbn = N >> 8;
  const int bm = blockIdx.x / nbn, bn = blockIdx.x % nbn;
  const int m0 = bm << 8, n0 = bn << 8;
  const int tid = threadIdx.x, lane = tid & 63;
  const int wid = tid >> 6;
  const int wm = wid >> 2, wn = wid & 3;      // 2 x 4 wave grid, 128x64/wave
  const int lr = lane & 15, lg = lane >> 4;

  f32x4 acc[8][4] = {};
  s16x8 aE[8], aO[8], bE[4], bO[4];

  // stage A region rh of tile ts into buf: rows (r>>6)*128 + rh*64 + (r&63)
  auto stA = [&](int buf, int rh, int ts) {
    const u16* src = A + (size_t)m0 * K + ts * 64;
    u16* dst = &As[buf][rh * 8192];
#pragma unroll
    for (int i = 0; i < 2; ++i) {
      int c = i * 512 + tid;
      int r = c >> 3, cr = c & 7;
      int grow = ((r >> 6) << 7) | (rh << 6) | (r & 63);
      int g = cr ^ (r & 7);
      gload_lds16(src + (size_t)grow * K + (g << 3), dst + c * 8);
    }
  };
  // stage B region rh: rows (r>>5)*64 + rh*32 + (r&31)
  auto stB = [&](int buf, int rh, int ts) {
    const u16* src = B + (size_t)n0 * K + ts * 64;
    u16* dst = &Bs[buf][rh * 8192];
#pragma unroll
    for (int i = 0; i < 2; ++i) {
      int c = i * 512 + tid;
      int r = c >> 3, cr = c & 7;
      int grow = ((r >> 5) << 6) | (rh << 5) | (r & 31);
      int g = cr ^ (r & 7);
      gload_lds16(src + (size_t)grow * K + (g << 3), dst + c * 8);
    }
  };
  // read A quadrant mh (4 mfrags x 2 kk = 8 x ds_read_b128), region mh
  auto rdA = [&](int buf, int mh, s16x8* d) {
#pragma unroll
    for (int i = 0; i < 4; ++i)
#pragma unroll
      for (int kk = 0; kk < 2; ++kk) {
        int sr = wm * 64 + i * 16 + lr;
        int jj = (kk * 4 + lg) ^ (sr & 7);
        d[i * 2 + kk] = *(const s16x8*)&As[buf][mh * 8192 + sr * 64 + (jj << 3)];
      }
  };
  // read B quadrant nh (2 nfrags x 2 kk = 4 x ds_read_b128), region nh
  auto rdB = [&](int buf, int nh, s16x8* d) {
#pragma unroll
    for (int j = 0; j < 2; ++j)
#pragma unroll
      for (int kk = 0; kk < 2; ++kk) {
        int sr = wn * 32 + j * 16 + lr;
        int jj = (kk * 4 + lg) ^ (sr & 7);
        d[j * 2 + kk] = *(const s16x8*)&Bs[buf][nh * 8192 + sr * 64 + (jj << 3)];
      }
  };
  // one C-quadrant x K=64 = 16 MFMA
  auto MF = [&](int mh, int nh, const s16x8* a, const s16x8* b) {
    __builtin_amdgcn_s_setprio(1);
#pragma unroll
    for (int i = 0; i < 4; ++i)
#pragma unroll
      for (int j = 0; j < 2; ++j)
#pragma unroll
        for (int kk = 0; kk < 2; ++kk)
          acc[mh * 4 + i][nh * 2 + j] =
              mfma16(a[i * 2 + kk], b[j * 2 + kk], acc[mh * 4 + i][nh * 2 + j]);
    __builtin_amdgcn_s_setprio(0);
  };

  const int nt = K >> 6;

  // prologue: tile0 (buf0) then tile1 (buf1, A0 first). 16 vm-ops issued;
  // VMC6 drains oldest 10 = all of t0 + A0(t1); {B0,B1,A1}(t1) stay flying.
  stA(0, 0, 0); stB(0, 0, 0); stB(0, 1, 0); stA(0, 1, 0);
  stA(1, 0, 1); stB(1, 0, 1); stB(1, 1, 1); stA(1, 1, 1);
  VMC6();
  BAR();
  rdA(0, 0, aE);      // A0(0) pre-read
  LGK0();
  BAR();              // all waves' A0(0) reads done before ph1 stage

#pragma unroll 1
  for (int it = 0; it < (nt >> 1); ++it) {
    const int u = it << 1;
    const int s2 = (u + 2 < nt) ? u + 2 : nt - 1;
    const int s3 = (u + 3 < nt) ? u + 3 : nt - 1;

    // ph1
    rdB(0, 0, bE); stA(0, 0, s2); BAR(); LGK0();
    MF(0, 0, aE, bE); BAR();
    // ph2
    rdB(0, 1, bO); stB(0, 0, s2); BAR(); LGK0();
    MF(0, 1, aE, bO); BAR();
    // ph3
    rdA(0, 1, aO); stB(0, 1, s2); BAR(); LGK0();
    MF(1, 1, aO, bO); BAR();
    // ph4
    rdA(1, 0, aE); stA(0, 1, s2); BAR(); LGK0();
    MF(1, 0, aO, bE); VMC6(); BAR();
    // ph5
    rdB(1, 0, bE); stA(1, 0, s3); BAR(); LGK0();
    MF(0, 0, aE, bE); BAR();
    // ph6
    rdB(1, 1, bO); stB(1, 0, s3); BAR(); LGK0();
    MF(0, 1, aE, bO); BAR();
    // ph7
    rdA(1, 1, aO); stB(1, 1, s3); BAR(); LGK0();
    MF(1, 1, aO, bO); BAR();
    // ph8
    rdA(0, 0, aE); stA(1, 1, s3); BAR(); LGK0();
    MF(1, 0, aO, bE); VMC6(); BAR();
  }

  asm volatile("s_waitcnt vmcnt(0)" ::: "memory");

  // ---- epilogue ----
#pragma unroll
  for (int m = 0; m < 8; ++m) {
#pragma unroll
    for (int n = 0; n < 4; ++n) {
      int col = n0 + wn * 64 + n * 16 + lr;
#pragma unroll
      for (int r = 0; r < 4; ++r) {
        int row = m0 + wm * 128 + m * 16 + lg * 4 + r;
        size_t idx = (size_t)row * N + col;
        float v = acc[m][n][r];
        if (EPI == 0) {
          ((u16*)Cout)[idx] = f2bf(v);
        } else if (EPI == 1) {
          float up = bf2f(((u16*)Cout)[idx]);
          float s = v / (1.0f + __expf(-v));
          ((u16*)Cout)[idx] = f2bf(s * up);
        } else if (EPI == 2) {
          ((float*)Cout)[idx] = aux[idx] + v;
        } else {
          ((float*)Cout)[idx] += v;
        }
      }
    }
  }
}

// ---------------- Flash attention (causal, in-block balanced) --------------
// r9: block p owns q-tiles lo=p and hi=31-p; every block does 33 work units.
// r12: T13 defer-max (THR=8). r14: single-Vt + two barriers (dbuf regressed);
// XCD-group swizzle (16 blocks sharing one (b,h)'s KV land on one XCD -> KV
// L2-resident; FETCH 269MB -> collapsed).
#define QBLK 128
#define KVBLK 64

__global__ __launch_bounds__(256, 2)
void attn_kernel(const u16* __restrict__ QKV, u16* __restrict__ O)
{
  __shared__ u16 Ks[2][KVBLK * HEADDIM];   // 32KB dbuf, chunk ^= row&7
  __shared__ u16 Vt[HEADDIM * KVBLK];      // 16KB single, transposed
  __shared__ u16 Pw[4][32 * KVBLK];        // 16KB per-wave P

  const int bid = blockIdx.x;
  const int swz = ((bid & 7) << 6) | (bid >> 3);   // XCD-group swizzle
  const int p  = swz & 15;                 // pair index
  const int h  = (swz >> 4) & (NHEADS - 1);
  const int b  = swz >> 8;
  const int tid = threadIdx.x, lane = tid & 63, wid = tid >> 6;
  const int lr = lane & 15, lg = lane >> 4;
  const size_t tokbase = (size_t)b * SEQ;
  const int hoff = h * HEADDIM;
  const int qrow0 = p * 64 + wid * 16;         // m=0 rows (lo tile)
  const int qrow1 = (31 - p) * 64 + wid * 16;  // m=1 rows (hi tile)
  const int nkb = 32 - p;
  const float scale = 0.08838834764831845f;

  s16x8 qf[2][4];
#pragma unroll
  for (int c = 0; c < 4; ++c) {
    qf[0][c] = *(const s16x8*)(QKV + (tokbase + qrow0 + lr) * QKV_RS
                               + hoff + c * 32 + lg * 8);
    qf[1][c] = *(const s16x8*)(QKV + (tokbase + qrow1 + lr) * QKV_RS
                               + hoff + c * 32 + lg * 8);
  }

  f32x4 o_acc[2][8] = {};
  float m_run[2][4], l_run[2][4];
#pragma unroll
  for (int m = 0; m < 2; ++m)
#pragma unroll
    for (int r = 0; r < 4; ++r) { m_run[m][r] = -1e30f; l_run[m][r] = 0.0f; }

  s16x8 v0[2], v1[2];

  // prologue: K tile 0 -> Ks[0], V tile 0 -> Vt
  {
    const u16* kbase = QKV + tokbase * QKV_RS + D_MODEL + hoff;
#pragma unroll
    for (int it = 0; it < 4; ++it) {
      int c = it * 256 + tid;
      int row = c >> 4, cr = c & 15;
      int g = cr ^ (row & 7);
      gload_lds16(kbase + (size_t)row * QKV_RS + g * 8, &Ks[0][c * 8]);
    }
    const u16* vbase = QKV + tokbase * QKV_RS + 2 * D_MODEL + hoff;
#pragma unroll
    for (int i = 0; i < 2; ++i) {
      int pi = i * 256 + tid;
      int rp = pi >> 4, dc = pi & 15;
      const u16* vp = vbase + (size_t)(rp * 2) * QKV_RS + dc * 8;
      v0[i] = *(const s16x8*)vp;
      v1[i] = *(const s16x8*)(vp + QKV_RS);
    }
    uint32_t* vt = (uint32_t*)&Vt[0];
#pragma unroll
    for (int i = 0; i < 2; ++i) {
      int pi = i * 256 + tid;
      int rp = pi >> 4, dc = pi & 15;
      int k0 = rp * 2;
      int base = ((k0 >> 3) ^ (dc & 7)) * 4 + ((k0 >> 1) & 3);
#pragma unroll
      for (int j = 0; j < 8; ++j)
        vt[(dc * 8 + j) * (KVBLK / 2) + base] =
            (uint32_t)(u16)v0[i][j] | ((uint32_t)(u16)v1[i][j] << 16);
    }
  }
  __syncthreads();

  for (int kb = 0; kb < nkb; ++kb) {
    const int buf = kb & 1;
    const bool nb = (kb + 1 < nkb);
    const bool act0 = (kb <= p);

    if (nb) {
      const u16* kbase = QKV + (tokbase + (size_t)(kb + 1) * KVBLK) * QKV_RS + D_MODEL + hoff;
#pragma unroll
      for (int it = 0; it < 4; ++it) {
        int c = it * 256 + tid;
        int row = c >> 4, cr = c & 15;
        int g = cr ^ (row & 7);
        gload_lds16(kbase + (size_t)row * QKV_RS + g * 8, &Ks[buf ^ 1][c * 8]);
      }
      const u16* vbase = QKV + (tokbase + (size_t)(kb + 1) * KVBLK) * QKV_RS + 2 * D_MODEL + hoff;
#pragma unroll
      for (int i = 0; i < 2; ++i) {
        int pi = i * 256 + tid;
        int rp = pi >> 4, dc = pi & 15;
        const u16* vp = vbase + (size_t)(rp * 2) * QKV_RS + dc * 8;
        v0[i] = *(const s16x8*)vp;
        v1[i] = *(const s16x8*)(vp + QKV_RS);
      }
    }

    // ---- QK^T ----
    f32x4 s_acc[2][4] = {};
#pragma unroll
    for (int kk = 0; kk < 4; ++kk) {
      s16x8 kf[4];
#pragma unroll
      for (int n = 0; n < 4; ++n) {
        int row = n * 16 + lr;
        int ch = (kk * 4 + lg) ^ (row & 7);
        kf[n] = *(const s16x8*)&Ks[buf][row * HEADDIM + ch * 8];
      }
#pragma unroll
      for (int m = 0; m < 2; ++m) {
        if (m == 0 && !act0) continue;
#pragma unroll
        for (int n = 0; n < 4; ++n)
          s_acc[m][n] = mfma16(qf[m][kk], kf[n], s_acc[m][n]);
      }
    }

    // ---- online softmax (defer-max, THR=8) ----
#pragma unroll
    for (int m = 0; m < 2; ++m) {
      if (m == 0 && !act0) continue;
      const int qb_ = (m == 0) ? qrow0 : qrow1;
      float tmax[4] = {-1e30f, -1e30f, -1e30f, -1e30f};
      float sv[4][4];
#pragma unroll
      for (int n = 0; n < 4; ++n) {
        int key = kb * KVBLK + n * 16 + lr;
#pragma unroll
        for (int r = 0; r < 4; ++r) {
          int q = qb_ + lg * 4 + r;
          float s = s_acc[m][n][r] * scale;
          if (key > q) s = -1e30f;
          sv[n][r] = s;
          tmax[r] = fmaxf(tmax[r], s);
        }
      }
#pragma unroll
      for (int o = 1; o < 16; o <<= 1)
#pragma unroll
        for (int r = 0; r < 4; ++r)
          tmax[r] = fmaxf(tmax[r], __shfl_xor(tmax[r], o));

      int small = (tmax[0] <= m_run[m][0] + 8.0f) &&
                  (tmax[1] <= m_run[m][1] + 8.0f) &&
                  (tmax[2] <= m_run[m][2] + 8.0f) &&
                  (tmax[3] <= m_run[m][3] + 8.0f);
      if (!__all(small)) {
        float pf[4];
#pragma unroll
        for (int r = 0; r < 4; ++r) {
          float mn = fmaxf(m_run[m][r], tmax[r]);
          pf[r] = __expf(m_run[m][r] - mn);
          m_run[m][r] = mn;
        }
#pragma unroll
        for (int r = 0; r < 4; ++r) l_run[m][r] *= pf[r];
#pragma unroll
        for (int t = 0; t < 8; ++t)
#pragma unroll
          for (int r = 0; r < 4; ++r)
            o_acc[m][t][r] *= pf[r];
      }

      float psum[4] = {0.0f, 0.0f, 0.0f, 0.0f};
#pragma unroll
      for (int n = 0; n < 4; ++n) {
        int keyl = n * 16 + lr;
#pragma unroll
        for (int r = 0; r < 4; ++r) {
          float pv = __expf(sv[n][r] - m_run[m][r]);
          psum[r] += pv;
          int ql = m * 16 + lg * 4 + r;
          int ch = (keyl >> 3) ^ (ql & 7);
          Pw[wid][ql * KVBLK + ch * 8 + (keyl & 7)] = f2bf(pv);
        }
      }
#pragma unroll
      for (int o = 1; o < 16; o <<= 1)
#pragma unroll
        for (int r = 0; r < 4; ++r)
          psum[r] += __shfl_xor(psum[r], o);
#pragma unroll
      for (int r = 0; r < 4; ++r)
        l_run[m][r] += psum[r];
    }

    // ---- PV ----
#pragma unroll
    for (int kk = 0; kk < 2; ++kk) {
      s16x8 pa[2];
#pragma unroll
      for (int m = 0; m < 2; ++m) {
        int ql = m * 16 + lr;
        int ch = (kk * 4 + lg) ^ (ql & 7);
        pa[m] = *(const s16x8*)&Pw[wid][ql * KVBLK + ch * 8];
      }
#pragma unroll
      for (int t = 0; t < 8; ++t) {
        int d = t * 16 + lr;
        int ch = (kk * 4 + lg) ^ ((d >> 3) & 7);
        s16x8 vf = *(const s16x8*)&Vt[d * KVBLK + ch * 8];
#pragma unroll
        for (int m = 0; m < 2; ++m) {
          if (m == 0 && !act0) continue;
          o_acc[m][t] = mfma16(pa[m], vf, o_acc[m][t]);
        }
      }
    }

    // single V buffer: wait for all waves' PV reads, then overwrite
    __syncthreads();
    if (nb) {
      uint32_t* vt = (uint32_t*)&Vt[0];
#pragma unroll
      for (int i = 0; i < 2; ++i) {
        int pi = i * 256 + tid;
        int rp = pi >> 4, dc = pi & 15;
        int k0 = rp * 2;
        int base = ((k0 >> 3) ^ (dc & 7)) * 4 + ((k0 >> 1) & 3);
#pragma unroll
        for (int j = 0; j < 8; ++j)
          vt[(dc * 8 + j) * (KVBLK / 2) + base] =
              (uint32_t)(u16)v0[i][j] | ((uint32_t)(u16)v1[i][j] << 16);
      }
    }
    __syncthreads();
  }

#pragma unroll
  for (int m = 0; m < 2; ++m)
#pragma unroll
    for (int t = 0; t < 8; ++t)
#pragma unroll
      for (int r = 0; r < 4; ++r) {
        int q = ((m == 0) ? qrow0 : qrow1) + lg * 4 + r;
        O[(tokbase + q) * D_MODEL + hoff + t * 16 + lr] =
            f2bf(o_acc[m][t][r] / l_run[m][r]);
      }
}

// ---------------------------------------------------------------------------
extern "C" void kernel_launch(void* const* d_in, const int* in_sizes, int n_in,
                              void* d_out, int out_size, void* d_ws, size_t ws_size,
                              hipStream_t stream)
{
  const float* hidden = (const float*)d_in[0];
  const float* wq    = (const float*)d_in[1];
  const float* wk    = (const float*)d_in[2];
  const float* wv    = (const float*)d_in[3];
  const float* wo    = (const float*)d_in[4];
  const float* wgate = (const float*)d_in[5];
  const float* wup   = (const float*)d_in[6];
  const float* wdown = (const float*)d_in[7];
  const float* ln1   = (const float*)d_in[8];
  const float* ln2   = (const float*)d_in[9];
  float* out = (float*)d_out;

  const size_t TD = (size_t)NTOK * D_MODEL;
  const size_t DD = (size_t)D_MODEL * D_MODEL;
  const size_t FD = (size_t)DFF * D_MODEL;

  u16* XN  = (u16*)d_ws;       // [NTOK, D]
  u16* QKV = XN + TD;          // [NTOK, 3D]  (later: w_up, then w_down)
  u16* AO  = QKV + 3 * TD;     // [NTOK, D]
  u16* WB  = AO + TD;          // wq|wk|wv|wo  (later: w_gate)
  u16* GU  = WB + FD;          // [NTOK, DFF]

  dim3 b256(256), b512(512);

  // all 4 attention weights in one launch
  cvt4_kernel<<<dim3(2048), b256, 0, stream>>>(
      wq, wk, wv, wo, WB + 0 * DD, WB + 1 * DD, WB + 2 * DD, WB + 3 * DD,
      (int)(DD / 4));

  rmsnorm_kernel<<<dim3(NTOK), b256, 0, stream>>>(hidden, ln1, XN);

  // fused QKV projection: [4096,2048] x [6144,2048]^T
  gemm256<0><<<dim3(16 * 24), b512, 0, stream>>>(XN, WB, QKV, nullptr, NTOK, 3 * D_MODEL, D_MODEL);

  attn_kernel<<<dim3(BATCH * NHEADS * (SEQ / QBLK)), b256, 0, stream>>>(QKV, AO);

  // out = hidden + AO @ wo^T   (N=2048 -> 128^2 kernel, 512 blocks)
  gemm_bt<2><<<dim3(32 * 16), b256, 0, stream>>>(AO, WB + 3 * DD, out, hidden, NTOK, D_MODEL, D_MODEL);

  // MLP weight conversions (gate+up batched)
  cvt2_kernel<<<dim3(4096), b256, 0, stream>>>(wgate, wup, WB, QKV, (int)(FD / 4));

  rmsnorm_kernel<<<dim3(NTOK), b256, 0, stream>>>(out, ln2, XN);

  gemm256<0><<<dim3(16 * 32), b512, 0, stream>>>(XN, QKV, GU, nullptr, NTOK, DFF, D_MODEL);
  gemm256<1><<<dim3(16 * 32), b512, 0, stream>>>(XN, WB, GU, nullptr, NTOK, DFF, D_MODEL);

  cvt_kernel<<<dim3(8192), b256, 0, stream>>>(wdown, QKV, (int)(FD / 4));

  // out += GU @ w_down^T   (N=2048 -> 128^2 kernel)
  gemm_bt<3><<<dim3(32 * 16), b256, 0, stream>>>(GU, QKV, out, nullptr, NTOK, D_MODEL, DFF);
}